// Round 1
// baseline (3267.836 us; speedup 1.0000x reference)
//
#include <hip/hip_runtime.h>
#include <math.h>

// out = gelu( (segment_sum(sem[src,0,:]) / max(cnt,1)) @ W )
// Linearity of W lets us aggregate raw semantics rows first, then apply the
// 128x128 GEMM once per node, fused with the mean and exact GELU.

// ---------------------------------------------------------------------------
// Scatter: 32 lanes per edge, each lane handles 4 contiguous floats (float4
// gather), 4 scalar float atomics into sums[tgt]. lane 0 bumps the count.
__global__ void scatter_kernel(const float* __restrict__ sem,
                               const int*   __restrict__ edges,
                               float* __restrict__ sums,
                               float* __restrict__ cnt,
                               int n_edges) {
    int t    = blockIdx.x * blockDim.x + threadIdx.x;
    int e    = t >> 5;
    int lane = t & 31;
    if (e >= n_edges) return;
    int s  = edges[2 * e];
    int tg = edges[2 * e + 1];
    // semantics is (n, 4, 128); row i, seq 0 starts at i*512 floats.
    const float4 v = ((const float4*)(sem + (size_t)s * 512))[lane];
    float* dst = sums + (size_t)tg * 128 + lane * 4;
    atomicAdd(dst + 0, v.x);
    atomicAdd(dst + 1, v.y);
    atomicAdd(dst + 2, v.z);
    atomicAdd(dst + 3, v.w);
    if (lane == 0) atomicAdd(cnt + tg, 1.0f);
}

// ---------------------------------------------------------------------------
// Finalize: per block, stage W (64 KB) in LDS once, then grid-stride over
// node rows (2 rows per 256-thread iteration). Each thread computes one
// output element: dot(mean_row, W[:,j]) -> exact gelu.
// LDS: 64KB W + 1KB mean => 2 blocks/CU.
__global__ void finalize_kernel(const float* __restrict__ sums,
                                const float* __restrict__ cnt,
                                const float* __restrict__ W,
                                float* __restrict__ out,
                                int n) {
    __shared__ float Wl[128 * 128];
    __shared__ float meanl[2 * 128];

    // cooperative load of W as float4 (4096 float4s / 256 threads = 16 each)
    for (int i = threadIdx.x; i < 128 * 32; i += blockDim.x)
        ((float4*)Wl)[i] = ((const float4*)W)[i];

    const int r = threadIdx.x >> 7;   // 0..1 : which row of the pair
    const int j = threadIdx.x & 127;  // output column
    const int rowsPerIter = 2 * gridDim.x;

    for (int row0 = blockIdx.x * 2; row0 < n; row0 += rowsPerIter) {
        const int row = row0 + r;
        __syncthreads();  // W ready (first iter) / meanl no longer in use
        if (row < n) {
            float c   = cnt[row];
            float inv = 1.0f / fmaxf(c, 1.0f);
            meanl[r * 128 + j] = sums[(size_t)row * 128 + j] * inv;
        }
        __syncthreads();
        if (row < n) {
            const float* m = meanl + r * 128;
            float acc = 0.0f;
            #pragma unroll 8
            for (int k = 0; k < 128; ++k)
                acc = fmaf(m[k], Wl[k * 128 + j], acc);
            // exact gelu: 0.5*x*(1+erf(x/sqrt(2)))
            float g = 0.5f * acc * (1.0f + erff(acc * 0.70710678118654752f));
            out[(size_t)row * 128 + j] = g;
        }
    }
}

// ---------------------------------------------------------------------------
extern "C" void kernel_launch(void* const* d_in, const int* in_sizes, int n_in,
                              void* d_out, int out_size, void* d_ws, size_t ws_size,
                              hipStream_t stream) {
    const float* sem   = (const float*)d_in[0];
    // d_in[1] (attention_masks) is unused by the reference.
    const float* W     = (const float*)d_in[2];
    const int*   edges = (const int*)d_in[3];

    const int n       = in_sizes[0] / (4 * 128);  // 100000
    const int n_edges = in_sizes[3] / 2;          // 1600000

    float* sums = (float*)d_ws;                        // n*128 floats
    float* cnt  = sums + (size_t)n * 128;              // n floats

    // zero the accumulators (ws is poisoned to 0xAA before every call)
    hipMemsetAsync(d_ws, 0, ((size_t)n * 128 + n) * sizeof(float), stream);

    const int threads = 256;
    const long long scatter_threads = (long long)n_edges * 32;
    const int sblocks = (int)((scatter_threads + threads - 1) / threads);
    scatter_kernel<<<sblocks, threads, 0, stream>>>(sem, edges, sums, cnt, n_edges);

    finalize_kernel<<<2048, threads, 0, stream>>>(sums, cnt, W, (float*)d_out, n);
}

// Round 2
// 707.818 us; speedup vs baseline: 4.6168x; 4.6168x over previous
//
#include <hip/hip_runtime.h>
#include <math.h>

// out = gelu( (segment_sum(sem[src,0,:]) / max(cnt,1)) @ W )
// R2: atomic scatter (2756us, 3.3GB HBM writes from line ping-pong) replaced
// by CSR build + atomic-free per-wave gather. Finalize register-blocked.

// ---------------------------------------------------------------------------
// Phase A1: degree histogram (int atomics, random over 100k targets)
__global__ void hist_kernel(const int* __restrict__ edges, int* __restrict__ deg,
                            int n_edges) {
    int e = blockIdx.x * blockDim.x + threadIdx.x;
    if (e < n_edges) {
        int2 p = ((const int2*)edges)[e];
        atomicAdd(&deg[p.y], 1);
    }
}

// Phase A2: per-block sums of degrees (1024 degs per block)
__global__ void scan_block_sums(const int* __restrict__ deg, int* __restrict__ bsums,
                                int n) {
    __shared__ int s[256];
    int base = blockIdx.x * 1024 + threadIdx.x * 4;
    int sum = 0;
    #pragma unroll
    for (int i = 0; i < 4; i++) { int idx = base + i; if (idx < n) sum += deg[idx]; }
    s[threadIdx.x] = sum;
    __syncthreads();
    for (int off = 128; off > 0; off >>= 1) {
        if (threadIdx.x < off) s[threadIdx.x] += s[threadIdx.x + off];
        __syncthreads();
    }
    if (threadIdx.x == 0) bsums[blockIdx.x] = s[0];
}

// Phase A3: exclusive scan of block sums (nb <= 128), also writes offs[n]=total
__global__ void scan_bsums(int* __restrict__ bsums, int* __restrict__ offs,
                           int nb, int n) {
    __shared__ int s[128];
    int v = (threadIdx.x < nb) ? bsums[threadIdx.x] : 0;
    s[threadIdx.x] = v;
    __syncthreads();
    for (int off = 1; off < 128; off <<= 1) {
        int t = (threadIdx.x >= off) ? s[threadIdx.x - off] : 0;
        __syncthreads();
        s[threadIdx.x] += t;
        __syncthreads();
    }
    if (threadIdx.x < nb) bsums[threadIdx.x] = (threadIdx.x == 0) ? 0 : s[threadIdx.x - 1];
    if (threadIdx.x == 0) offs[n] = s[127];
}

// Phase A4: local exclusive scan + block offset -> offs[], cursor[]
__global__ void scan_apply(const int* __restrict__ deg, const int* __restrict__ bsums,
                           int* __restrict__ offs, int* __restrict__ cursor, int n) {
    __shared__ int s[256];
    int base = blockIdx.x * 1024 + threadIdx.x * 4;
    int d[4]; int sum = 0;
    #pragma unroll
    for (int i = 0; i < 4; i++) { int idx = base + i; d[i] = (idx < n) ? deg[idx] : 0; sum += d[i]; }
    s[threadIdx.x] = sum;
    __syncthreads();
    for (int off = 1; off < 256; off <<= 1) {
        int t = (threadIdx.x >= off) ? s[threadIdx.x - off] : 0;
        __syncthreads();
        s[threadIdx.x] += t;
        __syncthreads();
    }
    int excl = bsums[blockIdx.x] + ((threadIdx.x == 0) ? 0 : s[threadIdx.x - 1]);
    #pragma unroll
    for (int i = 0; i < 4; i++) {
        int idx = base + i;
        if (idx < n) { offs[idx] = excl; cursor[idx] = excl; }
        excl += d[i];
    }
}

// Phase A5: scatter edge sources into CSR slots
__global__ void build_csr(const int* __restrict__ edges, int* __restrict__ cursor,
                          int* __restrict__ csr, int n_edges) {
    int e = blockIdx.x * blockDim.x + threadIdx.x;
    if (e < n_edges) {
        int2 p = ((const int2*)edges)[e];
        int pos = atomicAdd(&cursor[p.y], 1);
        csr[pos] = p.x;
    }
}

// ---------------------------------------------------------------------------
// Phase B: one wave per node. Lanes batch-load up to 64 csr indices
// (coalesced), __shfl-broadcast each, accumulate float2/lane. No atomics.
__global__ void gather_mean(const float* __restrict__ sem, const int* __restrict__ offs,
                            const int* __restrict__ csr, float* __restrict__ mean,
                            int n) {
    int gid  = blockIdx.x * blockDim.x + threadIdx.x;
    int wave = gid >> 6;
    int lane = gid & 63;
    if (wave >= n) return;
    int o0 = offs[wave], o1 = offs[wave + 1];
    int deg = o1 - o0;
    float2 acc = make_float2(0.f, 0.f);
    for (int c = 0; c < deg; c += 64) {
        int m  = min(64, deg - c);
        int sv = (lane < m) ? csr[o0 + c + lane] : 0;
        for (int j = 0; j < m; j++) {
            int s = __shfl(sv, j);
            const float2 v = ((const float2*)(sem + (size_t)s * 512))[lane];
            acc.x += v.x; acc.y += v.y;
        }
    }
    float inv = 1.0f / fmaxf((float)deg, 1.0f);
    ((float2*)(mean + (size_t)wave * 128))[lane] = make_float2(acc.x * inv, acc.y * inv);
}

// ---------------------------------------------------------------------------
// Phase C: out = gelu(mean @ W). 2 rows x 4 cols per thread (16 rows/iter),
// W staged once in LDS, mean tile restaged per iter. LDS 72KB -> 2 blocks/CU.
__device__ __forceinline__ float gelu_exact(float x) {
    return 0.5f * x * (1.0f + erff(x * 0.70710678118654752f));
}

__global__ __launch_bounds__(256, 2) void finalize_kernel(
    const float* __restrict__ mean, const float* __restrict__ W,
    float* __restrict__ out, int n) {
    __shared__ float Wl[128 * 128];
    __shared__ float ml[16 * 128];

    for (int i = threadIdx.x; i < 128 * 32; i += 256)
        ((float4*)Wl)[i] = ((const float4*)W)[i];

    const int r  = threadIdx.x >> 5;   // 0..7  -> rows r and r+8
    const int cg = threadIdx.x & 31;   // col group of 4
    const int rowsPerIter = 16 * gridDim.x;

    for (int row0 = blockIdx.x * 16; row0 < n; row0 += rowsPerIter) {
        __syncthreads();  // Wl ready (iter 0) / prev ml reads done
        #pragma unroll
        for (int p = 0; p < 2; p++) {
            int fid = threadIdx.x + 256 * p;   // 0..511 float4 slots
            int rr = fid >> 5, k4 = fid & 31;
            int row = row0 + rr;
            if (row < n)
                ((float4*)ml)[rr * 32 + k4] = ((const float4*)(mean + (size_t)row * 128))[k4];
        }
        __syncthreads();

        float4 a0 = make_float4(0.f, 0.f, 0.f, 0.f);
        float4 a1 = make_float4(0.f, 0.f, 0.f, 0.f);
        const float* m0 = ml + r * 128;
        const float* m1 = ml + (r + 8) * 128;
        #pragma unroll 4
        for (int k = 0; k < 128; k++) {
            float4 wv = ((const float4*)(Wl + k * 128))[cg];
            float v0 = m0[k], v1 = m1[k];
            a0.x = fmaf(v0, wv.x, a0.x); a0.y = fmaf(v0, wv.y, a0.y);
            a0.z = fmaf(v0, wv.z, a0.z); a0.w = fmaf(v0, wv.w, a0.w);
            a1.x = fmaf(v1, wv.x, a1.x); a1.y = fmaf(v1, wv.y, a1.y);
            a1.z = fmaf(v1, wv.z, a1.z); a1.w = fmaf(v1, wv.w, a1.w);
        }
        int row_a = row0 + r, row_b = row0 + r + 8;
        if (row_a < n) {
            float4 g = make_float4(gelu_exact(a0.x), gelu_exact(a0.y),
                                   gelu_exact(a0.z), gelu_exact(a0.w));
            ((float4*)(out + (size_t)row_a * 128))[cg] = g;
        }
        if (row_b < n) {
            float4 g = make_float4(gelu_exact(a1.x), gelu_exact(a1.y),
                                   gelu_exact(a1.z), gelu_exact(a1.w));
            ((float4*)(out + (size_t)row_b * 128))[cg] = g;
        }
    }
}

// ---------------------------------------------------------------------------
extern "C" void kernel_launch(void* const* d_in, const int* in_sizes, int n_in,
                              void* d_out, int out_size, void* d_ws, size_t ws_size,
                              hipStream_t stream) {
    const float* sem   = (const float*)d_in[0];
    const float* W     = (const float*)d_in[2];
    const int*   edges = (const int*)d_in[3];

    const int n       = in_sizes[0] / (4 * 128);  // 100000
    const int n_edges = in_sizes[3] / 2;          // 1600000

    // ws layout (16B-aligned sections)
    auto align16 = [](size_t x) { return (x + 15) & ~(size_t)15; };
    char* p = (char*)d_ws;
    int*   offs   = (int*)p;                    p += align16((size_t)(n + 1) * 4);
    int*   cursor = (int*)p;                    p += align16((size_t)n * 4);
    int*   deg    = (int*)p;                    p += align16((size_t)n * 4);
    int*   bsums  = (int*)p;                    p += align16(128 * 4);
    int*   csr    = (int*)p;                    p += align16((size_t)n_edges * 4);
    float* mean   = (float*)p;                  // n*128 floats

    // only deg needs zeroing; everything else is fully overwritten each call
    hipMemsetAsync(deg, 0, (size_t)n * 4, stream);

    const int T = 256;
    const int eblocks = (n_edges + T - 1) / T;          // 6250
    const int nb      = (n + 1023) / 1024;              // 98 (<=128)

    hist_kernel    <<<eblocks, T, 0, stream>>>(edges, deg, n_edges);
    scan_block_sums<<<nb,      T, 0, stream>>>(deg, bsums, n);
    scan_bsums     <<<1,     128, 0, stream>>>(bsums, offs, nb, n);
    scan_apply     <<<nb,      T, 0, stream>>>(deg, bsums, offs, cursor, n);
    build_csr      <<<eblocks, T, 0, stream>>>(edges, cursor, csr, n_edges);

    const int gblocks = (int)(((long long)n * 64 + T - 1) / T);  // 25000
    gather_mean    <<<gblocks, T, 0, stream>>>(sem, offs, csr, mean, n);

    finalize_kernel<<<512,     T, 0, stream>>>(mean, W, (float*)d_out, n);
}